// Round 1
// baseline (901.246 us; speedup 1.0000x reference)
//
#include <hip/hip_runtime.h>

// GiGCNConv: random-walk-normalized GCN conv with self loops.
// out[d] = b + sum_{e:(s->d)} (ew[e]/deg[d]) * (x[s]@W) + (1/deg[d]) * (x[d]@W)
// deg[d] = 1.0 + sum_{e:dst==d} ew[e]
//
// Inputs (harness order, dtypes per harness rules):
//   d_in[0] x           float32 [N*64]
//   d_in[1] edge_index  int32   [2*E]  (row 0 = src, row 1 = dst)
//   d_in[2] edge_weight float32 [E]
//   d_in[3] W           float32 [64*64]
//   d_in[4] b           float32 [64]
// Output: float32 [N*64]
// Workspace: deg/deg_inv (N f32, 64-elem aligned) + h (N*64 f32) ~= 26 MB

#define D 64

__global__ __launch_bounds__(256) void deg_kernel(const int* __restrict__ dst,
                                                  const float* __restrict__ ew,
                                                  float* __restrict__ deg, int E) {
    int t = blockIdx.x * blockDim.x + threadIdx.x;
    int stride = gridDim.x * blockDim.x;
    for (int e = t; e < E; e += stride) {
        atomicAdd(&deg[dst[e]], ew[e]);
    }
}

__global__ __launch_bounds__(256) void deginv_kernel(float* __restrict__ deg, int N) {
    int t = blockIdx.x * blockDim.x + threadIdx.x;
    int stride = gridDim.x * blockDim.x;
    for (int n = t; n < N; n += stride) {
        float tot = deg[n] + 1.0f;  // self-loop weight 1.0
        deg[n] = (tot > 0.0f) ? (1.0f / tot) : 0.0f;
    }
}

// h = x @ W. 4 rows per block, 64 threads per row (one per output column).
// W staged in LDS (16 KB); x rows staged in LDS for broadcast reads.
__global__ __launch_bounds__(256) void gemm_kernel(const float* __restrict__ x,
                                                   const float* __restrict__ W,
                                                   float* __restrict__ h, int N) {
    __shared__ float Ws[D * D];
    __shared__ float xs[4][D];
    int tid = threadIdx.x;
    for (int i = tid; i < D * D; i += 256) Ws[i] = W[i];
    int lr = tid >> 6;       // local row 0..3
    int j  = tid & 63;       // output column
    int r  = blockIdx.x * 4 + lr;
    if (r < N) xs[lr][j] = x[r * D + j];
    __syncthreads();
    if (r < N) {
        float sum = 0.0f;
#pragma unroll
        for (int k = 0; k < D; ++k) sum = fmaf(xs[lr][k], Ws[k * D + j], sum);
        h[r * D + j] = sum;
    }
}

// out = b + deg_inv * h   (bias + self-loop term), float4-vectorized.
__global__ __launch_bounds__(256) void init_kernel(const float* __restrict__ h,
                                                   const float* __restrict__ deginv,
                                                   const float* __restrict__ b,
                                                   float* __restrict__ out, int N) {
    int t = blockIdx.x * blockDim.x + threadIdx.x;
    int stride = gridDim.x * blockDim.x;
    int nq = N * (D / 4);
    const float4* h4 = (const float4*)h;
    const float4* b4 = (const float4*)b;
    float4* o4 = (float4*)out;
    for (int q = t; q < nq; q += stride) {
        int n  = q >> 4;       // node
        int c4 = q & 15;       // which float4 of the row
        float4 hv = h4[q];
        float4 bv = b4[c4];
        float di = deginv[n];
        float4 o;
        o.x = bv.x + di * hv.x;
        o.y = bv.y + di * hv.y;
        o.z = bv.z + di * hv.z;
        o.w = bv.w + di * hv.w;
        o4[q] = o;
    }
}

// One wave per edge iteration: lane j handles column j.
// out[dst][j] += deg_inv[dst] * ew * h[src][j]
__global__ __launch_bounds__(256) void scatter_kernel(const int* __restrict__ src,
                                                      const int* __restrict__ dst,
                                                      const float* __restrict__ ew,
                                                      const float* __restrict__ deginv,
                                                      const float* __restrict__ h,
                                                      float* __restrict__ out, int E) {
    int t = blockIdx.x * blockDim.x + threadIdx.x;
    int wave = t >> 6;
    int lane = t & 63;
    int nwaves = (gridDim.x * blockDim.x) >> 6;
    for (int e = wave; e < E; e += nwaves) {
        int s = src[e];
        int d = dst[e];
        float norm = deginv[d] * ew[e];
        atomicAdd(&out[d * D + lane], norm * h[s * D + lane]);
    }
}

extern "C" void kernel_launch(void* const* d_in, const int* in_sizes, int n_in,
                              void* d_out, int out_size, void* d_ws, size_t ws_size,
                              hipStream_t stream) {
    const float* x  = (const float*)d_in[0];
    const int*   ei = (const int*)d_in[1];
    const float* ew = (const float*)d_in[2];
    const float* W  = (const float*)d_in[3];
    const float* b  = (const float*)d_in[4];
    float* out = (float*)d_out;

    int N = in_sizes[0] / D;
    int E = in_sizes[2];
    const int* srcp = ei;       // edge_index[0]
    const int* dstp = ei + E;   // edge_index[1]

    // Workspace layout: deg (N floats, padded to 64-elem multiple), then h (N*D floats)
    float* deg = (float*)d_ws;
    int degPad = (N + 63) & ~63;
    float* h = deg + degPad;

    hipMemsetAsync(deg, 0, (size_t)N * sizeof(float), stream);

    deg_kernel<<<2048, 256, 0, stream>>>(dstp, ew, deg, E);
    deginv_kernel<<<(N + 255) / 256, 256, 0, stream>>>(deg, N);
    gemm_kernel<<<(N + 3) / 4, 256, 0, stream>>>(x, W, h, N);
    init_kernel<<<2048, 256, 0, stream>>>(h, deg, b, out, N);
    scatter_kernel<<<2048, 256, 0, stream>>>(srcp, dstp, ew, deg, h, out, E);
}

// Round 2
// 632.213 us; speedup vs baseline: 1.4255x; 1.4255x over previous
//
#include <hip/hip_runtime.h>

// GiGCNConv: out[d] = b + (1/deg[d]) * ( h[d] + sum_{e:(s->d)} ew[e]*h[s] )
//   h = x @ W,  deg[d] = 1 + sum_{e:dst==d} ew[e]
//
// Strategy: counting-sort edges by dst into CSR (pairs of {src, ew}), then
// one wave per destination node accumulates its segment in registers and
// writes out exactly once. No fp32 atomics on the output; deg computed
// inline from the segment. Fallback to atomic-scatter path if ws too small.
//
// Inputs: x f32[N*64], edge_index i32[2*E], edge_weight f32[E],
//         W f32[64*64], b f32[64].  Output f32[N*64].

#define D 64
#define SCAN_BLK 256

// ---------------- CSR build ----------------

__global__ __launch_bounds__(256) void count_kernel(const int* __restrict__ dst,
                                                    int* __restrict__ cnt, int E) {
    int t = blockIdx.x * blockDim.x + threadIdx.x;
    int stride = gridDim.x * blockDim.x;
    for (int e = t; e < E; e += stride) atomicAdd(&cnt[dst[e]], 1);
}

// per-block inclusive scan; partials -> part, block sums -> bsum
__global__ __launch_bounds__(SCAN_BLK) void scan1_kernel(const int* __restrict__ cnt,
                                                         int* __restrict__ part,
                                                         int* __restrict__ bsum, int N) {
    __shared__ int s[SCAN_BLK];
    int i = blockIdx.x * SCAN_BLK + threadIdx.x;
    int v = (i < N) ? cnt[i] : 0;
    s[threadIdx.x] = v;
    __syncthreads();
    for (int o = 1; o < SCAN_BLK; o <<= 1) {
        int t = (threadIdx.x >= (unsigned)o) ? s[threadIdx.x - o] : 0;
        __syncthreads();
        s[threadIdx.x] += t;
        __syncthreads();
    }
    if (i < N) part[i] = s[threadIdx.x];
    if (threadIdx.x == SCAN_BLK - 1) bsum[blockIdx.x] = s[threadIdx.x];
}

// single-block exclusive scan of bsum (G elements), in place
__global__ __launch_bounds__(SCAN_BLK) void scan2_kernel(int* __restrict__ bsum, int G) {
    __shared__ int s[SCAN_BLK];
    __shared__ int carry;
    if (threadIdx.x == 0) carry = 0;
    __syncthreads();
    for (int base = 0; base < G; base += SCAN_BLK) {
        int i = base + threadIdx.x;
        int v = (i < G) ? bsum[i] : 0;
        s[threadIdx.x] = v;
        __syncthreads();
        for (int o = 1; o < SCAN_BLK; o <<= 1) {
            int t = (threadIdx.x >= (unsigned)o) ? s[threadIdx.x - o] : 0;
            __syncthreads();
            s[threadIdx.x] += t;
            __syncthreads();
        }
        int incl = s[threadIdx.x];
        if (i < G) bsum[i] = carry + incl - v;  // exclusive
        __syncthreads();
        if (threadIdx.x == SCAN_BLK - 1) carry += incl;  // += chunk total
        __syncthreads();
    }
}

// off[i] = exclusive scan of cnt; cursor[i] = off[i]
__global__ __launch_bounds__(SCAN_BLK) void scan3_kernel(const int* __restrict__ cnt,
                                                         int* __restrict__ part_off,
                                                         int* __restrict__ cursor,
                                                         const int* __restrict__ bsum, int N) {
    int i = blockIdx.x * SCAN_BLK + threadIdx.x;
    if (i < N) {
        int ex = part_off[i] - cnt[i] + bsum[blockIdx.x];
        part_off[i] = ex;
        cursor[i] = ex;
    }
}

__global__ __launch_bounds__(256) void scatter_pass_kernel(const int* __restrict__ src,
                                                           const int* __restrict__ dst,
                                                           const float* __restrict__ ew,
                                                           int* __restrict__ cursor,
                                                           int2* __restrict__ pairs, int E) {
    int t = blockIdx.x * blockDim.x + threadIdx.x;
    int stride = gridDim.x * blockDim.x;
    for (int e = t; e < E; e += stride) {
        int d = dst[e];
        int pos = atomicAdd(&cursor[d], 1);
        pairs[pos] = make_int2(src[e], __float_as_int(ew[e]));
    }
}

// ---------------- h = x @ W ----------------

__global__ __launch_bounds__(256) void gemm_kernel(const float* __restrict__ x,
                                                   const float* __restrict__ W,
                                                   float* __restrict__ h, int N) {
    __shared__ float Ws[D * D];
    __shared__ float xs[4][D];
    int tid = threadIdx.x;
    for (int i = tid; i < D * D; i += 256) Ws[i] = W[i];
    int lr = tid >> 6;
    int j  = tid & 63;
    int r  = blockIdx.x * 4 + lr;
    if (r < N) xs[lr][j] = x[r * D + j];
    __syncthreads();
    if (r < N) {
        float sum = 0.0f;
#pragma unroll
        for (int k = 0; k < D; ++k) sum = fmaf(xs[lr][k], Ws[k * D + j], sum);
        h[r * D + j] = sum;
    }
}

// ---------------- accumulate: one wave per node ----------------

__global__ __launch_bounds__(256) void accum_kernel(const int2* __restrict__ pairs,
                                                    const int* __restrict__ off,
                                                    const int* __restrict__ cnt,
                                                    const float* __restrict__ h,
                                                    const float* __restrict__ b,
                                                    float* __restrict__ out, int N) {
    int t = blockIdx.x * blockDim.x + threadIdx.x;
    int n = t >> 6;
    int j = t & 63;
    if (n >= N) return;
    int base = off[n];
    int c = cnt[n];
    float acc = h[(size_t)n * D + j];  // self loop (weight 1)
    float degs = 1.0f;
    int i = 0;
    for (; i + 1 < c; i += 2) {
        int2 p0 = pairs[base + i];
        int2 p1 = pairs[base + i + 1];
        float w0 = __int_as_float(p0.y);
        float w1 = __int_as_float(p1.y);
        float h0 = h[(size_t)p0.x * D + j];
        float h1 = h[(size_t)p1.x * D + j];
        degs += w0 + w1;
        acc = fmaf(w0, h0, acc);
        acc = fmaf(w1, h1, acc);
    }
    if (i < c) {
        int2 p = pairs[base + i];
        float w = __int_as_float(p.y);
        degs += w;
        acc = fmaf(w, h[(size_t)p.x * D + j], acc);
    }
    float di = (degs > 0.0f) ? (1.0f / degs) : 0.0f;
    out[(size_t)n * D + j] = fmaf(di, acc, b[j]);
}

// ---------------- fallback (atomic scatter, round-1 path) ----------------

__global__ __launch_bounds__(256) void deg_kernel(const int* __restrict__ dst,
                                                  const float* __restrict__ ew,
                                                  float* __restrict__ deg, int E) {
    int t = blockIdx.x * blockDim.x + threadIdx.x;
    int stride = gridDim.x * blockDim.x;
    for (int e = t; e < E; e += stride) atomicAdd(&deg[dst[e]], ew[e]);
}

__global__ __launch_bounds__(256) void deginv_kernel(float* __restrict__ deg, int N) {
    int t = blockIdx.x * blockDim.x + threadIdx.x;
    int stride = gridDim.x * blockDim.x;
    for (int n = t; n < N; n += stride) {
        float tot = deg[n] + 1.0f;
        deg[n] = (tot > 0.0f) ? (1.0f / tot) : 0.0f;
    }
}

__global__ __launch_bounds__(256) void init_kernel(const float* __restrict__ h,
                                                   const float* __restrict__ deginv,
                                                   const float* __restrict__ b,
                                                   float* __restrict__ out, int N) {
    int t = blockIdx.x * blockDim.x + threadIdx.x;
    int stride = gridDim.x * blockDim.x;
    int nq = N * (D / 4);
    const float4* h4 = (const float4*)h;
    const float4* b4 = (const float4*)b;
    float4* o4 = (float4*)out;
    for (int q = t; q < nq; q += stride) {
        int n = q >> 4;
        int c4 = q & 15;
        float4 hv = h4[q];
        float4 bv = b4[c4];
        float di = deginv[n];
        float4 o;
        o.x = bv.x + di * hv.x;
        o.y = bv.y + di * hv.y;
        o.z = bv.z + di * hv.z;
        o.w = bv.w + di * hv.w;
        o4[q] = o;
    }
}

__global__ __launch_bounds__(256) void scatter_kernel(const int* __restrict__ src,
                                                      const int* __restrict__ dst,
                                                      const float* __restrict__ ew,
                                                      const float* __restrict__ deginv,
                                                      const float* __restrict__ h,
                                                      float* __restrict__ out, int E) {
    int t = blockIdx.x * blockDim.x + threadIdx.x;
    int wave = t >> 6;
    int lane = t & 63;
    int nwaves = (gridDim.x * blockDim.x) >> 6;
    for (int e = wave; e < E; e += nwaves) {
        int s = src[e];
        int d = dst[e];
        float norm = deginv[d] * ew[e];
        atomicAdd(&out[d * D + lane], norm * h[s * D + lane]);
    }
}

// ---------------- launcher ----------------

extern "C" void kernel_launch(void* const* d_in, const int* in_sizes, int n_in,
                              void* d_out, int out_size, void* d_ws, size_t ws_size,
                              hipStream_t stream) {
    const float* x  = (const float*)d_in[0];
    const int*   ei = (const int*)d_in[1];
    const float* ew = (const float*)d_in[2];
    const float* W  = (const float*)d_in[3];
    const float* b  = (const float*)d_in[4];
    float* out = (float*)d_out;

    int N = in_sizes[0] / D;
    int E = in_sizes[2];
    const int* srcp = ei;
    const int* dstp = ei + E;

    size_t Npad = ((size_t)N + 63) & ~(size_t)63;
    int G1 = (N + SCAN_BLK - 1) / SCAN_BLK;
    size_t Gpad = ((size_t)G1 + 63) & ~(size_t)63;

    // CSR layout: cnt | off | cursor | bsum | h | pairs
    size_t need = (3 * Npad + Gpad) * 4 + (size_t)N * D * 4 + (size_t)E * 8;

    if (ws_size >= need) {
        int* cnt    = (int*)d_ws;
        int* off    = cnt + Npad;
        int* cursor = off + Npad;
        int* bsum   = cursor + Npad;
        float* h    = (float*)(bsum + Gpad);
        int2* pairs = (int2*)(h + (size_t)N * D);

        hipMemsetAsync(cnt, 0, Npad * 4, stream);
        count_kernel<<<2048, 256, 0, stream>>>(dstp, cnt, E);
        scan1_kernel<<<G1, SCAN_BLK, 0, stream>>>(cnt, off, bsum, N);
        scan2_kernel<<<1, SCAN_BLK, 0, stream>>>(bsum, G1);
        scan3_kernel<<<G1, SCAN_BLK, 0, stream>>>(cnt, off, cursor, bsum, N);
        scatter_pass_kernel<<<2048, 256, 0, stream>>>(srcp, dstp, ew, cursor, pairs, E);
        gemm_kernel<<<(N + 3) / 4, 256, 0, stream>>>(x, W, h, N);
        accum_kernel<<<(N + 3) / 4, 256, 0, stream>>>(pairs, off, cnt, h, b, out, N);
    } else {
        // fallback: atomic scatter (round-1 path), needs deg + h only
        float* deg = (float*)d_ws;
        float* h = deg + Npad;
        hipMemsetAsync(deg, 0, (size_t)N * sizeof(float), stream);
        deg_kernel<<<2048, 256, 0, stream>>>(dstp, ew, deg, E);
        deginv_kernel<<<(N + 255) / 256, 256, 0, stream>>>(deg, N);
        gemm_kernel<<<(N + 3) / 4, 256, 0, stream>>>(x, W, h, N);
        init_kernel<<<2048, 256, 0, stream>>>(h, deg, b, out, N);
        scatter_kernel<<<2048, 256, 0, stream>>>(srcp, dstp, ew, deg, h, out, E);
    }
}